// Round 1
// baseline (87711.053 us; speedup 1.0000x reference)
//
#include <hip/hip_runtime.h>
#include <hip/hip_bf16.h>
#include <math.h>

// Problem: 3-layer masked BiLSTM (B=32,T=1024,D=1024,H=512) + 4 heads.
// Round 1: all-fp32 correctness baseline.
//   - gemm_bias_f32: z = in @ W + b   (tiled 64x64x16, 4x4 per thread)
//   - lstm_step:     one launch per timestep, both directions; each block
//                    owns 8 hidden units x 4 gates x 32 batches so the gate
//                    nonlinearities + state update complete in-kernel.
//   - heads_kernel:  relu + 4 linear heads + 2-class softmax.

#define B_ 32
#define T_ 1024
#define H_ 512
#define DIN 1024
#define NG 2048   // 4*H

// ---------------------------------------------------------------- zero states
__global__ void zero_states(float* __restrict__ s) {
    s[blockIdx.x * 256 + threadIdx.x] = 0.0f;
}

// ---------------------------------------------------------------- input GEMM
// A: [B,T,1024] fp32 (activations), W: [1024,2048], bias: [2048]
// Z: [B*C, 2048] rows m = b*C + (t - t0), reading A row b*T + t0 + (m & (C-1))
#define GBM 64
#define GBN 64
#define GBK 16
__global__ __launch_bounds__(256) void gemm_bias_f32(
    const float* __restrict__ A, const float* __restrict__ W,
    const float* __restrict__ bias, float* __restrict__ Z,
    int t0, int lgC) {
    __shared__ float sA[GBK][GBM + 4];
    __shared__ float sB[GBK][GBN + 4];
    const int m0 = blockIdx.y * GBM;
    const int n0 = blockIdx.x * GBN;
    const int tid = threadIdx.x;
    const int tx = tid & 15, ty = tid >> 4;
    const int Cmask = (1 << lgC) - 1;
    float acc[4][4] = {};

    // staging indices (constant across k loop)
    const int mm = tid >> 2, ko = (tid & 3) * 4;      // A tile loader
    const int m = m0 + mm;
    const size_t rowg = (size_t)(m >> lgC) * T_ + t0 + (m & Cmask);
    const int kk = tid >> 4, no = (tid & 15) * 4;     // B tile loader

    for (int kc = 0; kc < DIN; kc += GBK) {
        float4 av = *(const float4*)&A[rowg * DIN + kc + ko];
        sA[ko + 0][mm] = av.x; sA[ko + 1][mm] = av.y;
        sA[ko + 2][mm] = av.z; sA[ko + 3][mm] = av.w;
        float4 bv = *(const float4*)&W[(size_t)(kc + kk) * NG + n0 + no];
        *(float4*)&sB[kk][no] = bv;
        __syncthreads();
#pragma unroll
        for (int k = 0; k < GBK; k++) {
            float4 a4 = *(float4*)&sA[k][ty * 4];
            float4 b4 = *(float4*)&sB[k][tx * 4];
            acc[0][0] += a4.x * b4.x; acc[0][1] += a4.x * b4.y;
            acc[0][2] += a4.x * b4.z; acc[0][3] += a4.x * b4.w;
            acc[1][0] += a4.y * b4.x; acc[1][1] += a4.y * b4.y;
            acc[1][2] += a4.y * b4.z; acc[1][3] += a4.y * b4.w;
            acc[2][0] += a4.z * b4.x; acc[2][1] += a4.z * b4.y;
            acc[2][2] += a4.z * b4.z; acc[2][3] += a4.z * b4.w;
            acc[3][0] += a4.w * b4.x; acc[3][1] += a4.w * b4.y;
            acc[3][2] += a4.w * b4.z; acc[3][3] += a4.w * b4.w;
        }
        __syncthreads();
    }
#pragma unroll
    for (int i = 0; i < 4; i++) {
        int mo = m0 + ty * 4 + i;
#pragma unroll
        for (int j = 0; j < 4; j++) {
            int n = n0 + tx * 4 + j;
            Z[(size_t)mo * NG + n] = acc[i][j] + bias[n];
        }
    }
}

// ---------------------------------------------------------------- LSTM step
// grid: (H/8, 2).  block 256.  Each block: u-slice of 8 units, all 4 gates,
// all 32 batches.  rec = h @ U[:, {g*512+u0 .. +8, g=0..3}], then gates.
__global__ __launch_bounds__(256) void lstm_step(
    const float* __restrict__ zf, const float* __restrict__ zb,
    const float* __restrict__ Uf, const float* __restrict__ Ub,
    const int* __restrict__ xmask,
    float* __restrict__ hf, float* __restrict__ cf,
    float* __restrict__ hb, float* __restrict__ cb,
    float* __restrict__ hseq,
    int tf, int tb, int t0f, int t0b, int C) {
    const int dir = blockIdx.y;
    const float* z = dir ? zb : zf;
    const float* U = dir ? Ub : Uf;
    float* h = dir ? hb : hf;
    float* c = dir ? cb : cf;
    const int t = dir ? tb : tf;
    const int t0 = dir ? t0b : t0f;
    const int u0 = blockIdx.x * 8;

    __shared__ float sh[64 * 32];  // h chunk [k][b], reused for pre-activations
    __shared__ float su[64 * 32];  // U chunk [k][jj]  jj = gate*8+uu

    const int tid = threadIdx.x;
    const int jh = tid & 15;   // j-pair: jj = jh*2
    const int bh = tid >> 4;   // b-pair: b  = bh*2
    float a00 = 0, a01 = 0, a10 = 0, a11 = 0;

    for (int kc = 0; kc < H_; kc += 64) {
        {   // stage h[b][kc..kc+64] transposed -> sh[k][b]
            int b = tid & 31, kq = tid >> 5;
            const float* hp = &h[b * H_ + kc + kq * 8];
            float4 v0 = *(const float4*)hp;
            float4 v1 = *(const float4*)(hp + 4);
            int base = (kq * 8) * 32 + b;
            sh[base + 0 * 32] = v0.x; sh[base + 1 * 32] = v0.y;
            sh[base + 2 * 32] = v0.z; sh[base + 3 * 32] = v0.w;
            sh[base + 4 * 32] = v1.x; sh[base + 5 * 32] = v1.y;
            sh[base + 6 * 32] = v1.z; sh[base + 7 * 32] = v1.w;
            // stage U[kc+k][gate*512 + u0 .. +8] -> su[k][gate*8..]
            int k = tid >> 2, gate = tid & 3;
            const float* up = &U[(size_t)(kc + k) * NG + gate * H_ + u0];
            float4 u0v = *(const float4*)up;
            float4 u1v = *(const float4*)(up + 4);
            *(float4*)&su[k * 32 + gate * 8] = u0v;
            *(float4*)&su[k * 32 + gate * 8 + 4] = u1v;
        }
        __syncthreads();
#pragma unroll 16
        for (int k = 0; k < 64; k++) {
            float2 hv = *(float2*)&sh[k * 32 + bh * 2];
            float2 uv = *(float2*)&su[k * 32 + jh * 2];
            a00 += hv.x * uv.x; a01 += hv.x * uv.y;
            a10 += hv.y * uv.x; a11 += hv.y * uv.y;
        }
        __syncthreads();
    }
    {   // add z, park pre-activations in sh[b][jj]
        int b0 = bh * 2, jj0 = jh * 2;
        int tc = t - t0;
        const float* zr0 = &z[((size_t)b0 * C + tc) * NG];
        const float* zr1 = zr0 + (size_t)C * NG;
        int col = (jj0 >> 3) * H_ + u0 + (jj0 & 7);   // jj0 even -> same gate as jj0+1
        sh[b0 * 32 + jj0]           = a00 + zr0[col];
        sh[b0 * 32 + jj0 + 1]       = a01 + zr0[col + 1];
        sh[(b0 + 1) * 32 + jj0]     = a10 + zr1[col];
        sh[(b0 + 1) * 32 + jj0 + 1] = a11 + zr1[col + 1];
    }
    __syncthreads();
    {   // gates + state update, one (b,u) per thread
        int b = tid >> 3, uu = tid & 7;
        float zi = sh[b * 32 + uu];
        float zff = sh[b * 32 + 8 + uu];
        float zg = sh[b * 32 + 16 + uu];
        float zo = sh[b * 32 + 24 + uu];
        float iv = 1.0f / (1.0f + expf(-zi));
        float fv = 1.0f / (1.0f + expf(-zff));
        float gv = tanhf(zg);
        float ov = 1.0f / (1.0f + expf(-zo));
        int u = u0 + uu;
        bool valid = (xmask[b * T_ + t] != 1);
        float hn;
        if (valid) {
            float co = c[b * H_ + u];
            float cn = fv * co + iv * gv;
            hn = ov * tanhf(cn);
            c[b * H_ + u] = cn;
            h[b * H_ + u] = hn;
        } else {
            hn = h[b * H_ + u];
        }
        hseq[((size_t)b * T_ + t) * DIN + dir * H_ + u] = hn;
    }
}

// ---------------------------------------------------------------- heads
__global__ __launch_bounds__(256) void heads_kernel(
    const float* __restrict__ xin,
    const float* __restrict__ Wp, const float* __restrict__ bp,
    const float* __restrict__ Wbu, const float* __restrict__ bbu,
    const float* __restrict__ Wss3, const float* __restrict__ bss3,
    const float* __restrict__ Wss8, const float* __restrict__ bss8,
    float* __restrict__ out) {
    const int r = blockIdx.x * 4 + (threadIdx.x >> 6);
    const int lane = threadIdx.x & 63;
    const float* xr = &xin[(size_t)r * DIN + lane * 16];
    float xv[16];
#pragma unroll
    for (int i = 0; i < 4; i++) {
        float4 v = *(const float4*)&xr[i * 4];
        xv[i * 4 + 0] = fmaxf(v.x, 0.0f); xv[i * 4 + 1] = fmaxf(v.y, 0.0f);
        xv[i * 4 + 2] = fmaxf(v.z, 0.0f); xv[i * 4 + 3] = fmaxf(v.w, 0.0f);
    }
    float acc[15] = {};
    const int k0 = lane * 16;
#pragma unroll
    for (int kk = 0; kk < 16; kk++) {
        float xk = xv[kk];
        int k = k0 + kk;
        acc[0] += xk * Wp[k * 2];      acc[1] += xk * Wp[k * 2 + 1];
        acc[2] += xk * Wbu[k * 2];     acc[3] += xk * Wbu[k * 2 + 1];
        acc[4] += xk * Wss3[k * 3];    acc[5] += xk * Wss3[k * 3 + 1];
        acc[6] += xk * Wss3[k * 3 + 2];
#pragma unroll
        for (int o = 0; o < 8; o++) acc[7 + o] += xk * Wss8[k * 8 + o];
    }
#pragma unroll
    for (int o = 0; o < 15; o++) {
#pragma unroll
        for (int off = 32; off; off >>= 1) acc[o] += __shfl_xor(acc[o], off, 64);
    }
    if (lane == 0) {
        float a0 = acc[0] + bp[0], a1 = acc[1] + bp[1];
        float mx = fmaxf(a0, a1);
        float e0 = expf(a0 - mx), e1 = expf(a1 - mx);
        float s = e0 + e1;
        out[(size_t)r * 2] = e0 / s;
        out[(size_t)r * 2 + 1] = e1 / s;
        float* ob = out + 65536;
        ob[r * 2] = acc[2] + bbu[0]; ob[r * 2 + 1] = acc[3] + bbu[1];
        float* o3 = out + 131072;
        o3[r * 3 + 0] = acc[4] + bss3[0];
        o3[r * 3 + 1] = acc[5] + bss3[1];
        o3[r * 3 + 2] = acc[6] + bss3[2];
        float* o8 = out + 229376;
#pragma unroll
        for (int o = 0; o < 8; o++) o8[r * 8 + o] = acc[7 + o] + bss8[o];
    }
}

// ---------------------------------------------------------------- launch
extern "C" void kernel_launch(void* const* d_in, const int* in_sizes, int n_in,
                              void* d_out, int out_size, void* d_ws, size_t ws_size,
                              hipStream_t stream) {
    const float* x = (const float*)d_in[0];
    const int* xmask = (const int*)d_in[1];
    const float* Wf = (const float*)d_in[2];
    const float* Uf = (const float*)d_in[3];
    const float* bfp = (const float*)d_in[4];
    const float* Wb = (const float*)d_in[5];
    const float* Ub = (const float*)d_in[6];
    const float* bbp = (const float*)d_in[7];
    const float* Wp = (const float*)d_in[8];
    const float* bp = (const float*)d_in[9];
    const float* Wbu = (const float*)d_in[10];
    const float* bbu = (const float*)d_in[11];
    const float* Wss3 = (const float*)d_in[12];
    const float* bss3 = (const float*)d_in[13];
    const float* Wss8 = (const float*)d_in[14];
    const float* bss8 = (const float*)d_in[15];

    float* ws = (float*)d_ws;
    const size_t bufElems = (size_t)B_ * T_ * DIN;   // 33.55M floats = 128MB
    float* bufA = ws;
    float* bufB = ws + bufElems;
    float* states = ws + 2 * bufElems;               // 4*B*H floats
    float* zf = states + 4 * B_ * H_;

    // pick time-chunk C for z buffers based on available workspace
    size_t fixedBytes = (2 * bufElems + 4 * B_ * H_) * 4;
    int C = 1024;
    while (C > 32 && fixedBytes + (size_t)2 * B_ * C * NG * 4 > ws_size) C >>= 1;
    float* zb = zf + (size_t)B_ * C * NG;
    int lgC = 31 - __builtin_clz(C);

    const float* cur = x;
    float* nxt = bufA;
    float* other = bufB;
    for (int l = 0; l < 3; l++) {
        zero_states<<<dim3(256), dim3(256), 0, stream>>>(states);
        const float* Wfl = Wf + (size_t)l * DIN * NG;
        const float* Wbl = Wb + (size_t)l * DIN * NG;
        const float* Ufl = Uf + (size_t)l * H_ * NG;
        const float* Ubl = Ub + (size_t)l * H_ * NG;
        const float* bfl = bfp + l * NG;
        const float* bbl = bbp + l * NG;
        float* hf = states;
        float* cf = states + B_ * H_;
        float* hb = states + 2 * B_ * H_;
        float* cb = states + 3 * B_ * H_;
        for (int c0 = 0; c0 < T_; c0 += C) {
            int t0f = c0;
            int t0b = T_ - c0 - C;
            dim3 ggrid(NG / GBN, (B_ * C) / GBM);
            gemm_bias_f32<<<ggrid, 256, 0, stream>>>(cur, Wfl, bfl, zf, t0f, lgC);
            gemm_bias_f32<<<ggrid, 256, 0, stream>>>(cur, Wbl, bbl, zb, t0b, lgC);
            for (int s = 0; s < C; s++) {
                int tf = t0f + s;
                int tb = t0b + (C - 1 - s);
                lstm_step<<<dim3(H_ / 8, 2), 256, 0, stream>>>(
                    zf, zb, Ufl, Ubl, xmask, hf, cf, hb, cb, nxt,
                    tf, tb, t0f, t0b, C);
            }
        }
        cur = nxt;
        float* tmp = nxt; nxt = other; other = tmp;
    }
    heads_kernel<<<dim3(B_ * T_ / 4), 256, 0, stream>>>(
        cur, Wp, bp, Wbu, bbu, Wss3, bss3, Wss8, bss8, (float*)d_out);
}